// Round 10
// baseline (200.471 us; speedup 1.0000x reference)
//
#include <hip/hip_runtime.h>

typedef __attribute__((ext_vector_type(8))) short short8;
typedef __attribute__((ext_vector_type(4))) float f32x4;
typedef __attribute__((ext_vector_type(4))) unsigned short ushort4v;

struct DB0 { static constexpr int value = 0; };
struct DB1 { static constexpr int value = 1; };
struct DB2 { static constexpr int value = 2; };

__device__ __forceinline__ unsigned short f2bf(float f) {
  unsigned int u = __float_as_uint(f);
  u += 0x7fffu + ((u >> 16) & 1u);
  return (unsigned short)(u >> 16);
}
__device__ __forceinline__ float bf2f(unsigned short h) {
  return __uint_as_float(((unsigned int)h) << 16);
}

__device__ __forceinline__ void gload16(const unsigned short* g, unsigned short* l) {
  __builtin_amdgcn_global_load_lds(
      (const __attribute__((address_space(1))) unsigned int*)g,
      (__attribute__((address_space(3))) unsigned int*)l,
      16, 0, 0);
}

template <int OFF>
__device__ __forceinline__ short8 dsr(unsigned a) {
  short8 r;
  asm volatile("ds_read_b128 %0, %1 offset:%2" : "=v"(r) : "v"(a), "n"(OFF));
  return r;
}

__device__ __forceinline__ void bar() {
  asm volatile("" ::: "memory");
  __builtin_amdgcn_s_barrier();
  asm volatile("" ::: "memory");
}

// ---- merged prep: conv x->bf16 (8192 blks) | W_attn^T (3072) | W_proj^T (1024)
__global__ __launch_bounds__(256) void prep_kernel(
    const float* __restrict__ x, unsigned short* __restrict__ xb,
    const float* __restrict__ Wa, unsigned short* __restrict__ wta,
    const float* __restrict__ Wp, unsigned short* __restrict__ wtp) {
  int b = blockIdx.x;
  int tx = threadIdx.x & 31, ty = threadIdx.x >> 5;
  if (b < 8192) {
    int i = b * 256 + threadIdx.x;
    f32x4 v = ((const f32x4*)x)[i];
    ushort4v o;
    o[0] = f2bf(v[0]); o[1] = f2bf(v[1]); o[2] = f2bf(v[2]); o[3] = f2bf(v[3]);
    ((ushort4v*)xb)[i] = o;
    return;
  }
  const float* W; unsigned short* Wt; int K, N, n0, k0;
  if (b < 8192 + 3072) {
    int bb = b - 8192; W = Wa; Wt = wta; K = 1024; N = 3072;
    n0 = (bb % 96) * 32; k0 = (bb / 96) * 32;
  } else {
    int bb = b - 11264; W = Wp; Wt = wtp; K = 1024; N = 1024;
    n0 = (bb % 32) * 32; k0 = (bb / 32) * 32;
  }
  __shared__ float tile[32][33];
#pragma unroll
  for (int j = 0; j < 32; j += 8)
    tile[ty + j][tx] = W[(size_t)(k0 + ty + j) * N + n0 + tx];
  __syncthreads();
#pragma unroll
  for (int j = 0; j < 32; j += 8)
    Wt[(size_t)(n0 + ty + j) * K + k0 + tx] = f2bf(tile[tx][ty + j]);
}

// ------- row softmax on S (bf16, in place), causal-variable length -------
__global__ __launch_bounds__(256) void softmax_kernel(unsigned short* __restrict__ S) {
  int row = blockIdx.x * 4 + (threadIdx.x >> 6);
  int l = threadIdx.x & 63;
  int rl = row & 2047;
  int rend = ((rl >> 7) + 1) << 7;
  unsigned short* p = S + (size_t)row * 2048;
  float v[32];
  float mx = -3e38f;
#pragma unroll
  for (int i = 0; i < 4; i++) {
    int c0 = (i * 64 + l) * 8;
    if (c0 < rend) {
      short8 raw = *(const short8*)&p[c0];
#pragma unroll
      for (int j = 0; j < 8; j++) {
        v[i * 8 + j] = bf2f((unsigned short)raw[j]);
        mx = fmaxf(mx, v[i * 8 + j]);
      }
    } else {
#pragma unroll
      for (int j = 0; j < 8; j++) v[i * 8 + j] = -3e38f;
    }
  }
#pragma unroll
  for (int off = 1; off < 64; off <<= 1) mx = fmaxf(mx, __shfl_xor(mx, off));
  float s = 0.f;
#pragma unroll
  for (int i = 0; i < 32; i++) { v[i] = exp2f((v[i] - mx) * 1.44269504f); s += v[i]; }
#pragma unroll
  for (int off = 1; off < 64; off <<= 1) s += __shfl_xor(s, off);
  float inv = 1.f / s;
#pragma unroll
  for (int i = 0; i < 4; i++) {
    int c0 = (i * 64 + l) * 8;
    if (c0 < rend) {
      short8 o;
#pragma unroll
      for (int j = 0; j < 8; j++) o[j] = (short)f2bf(v[i * 8 + j] * inv);
      *(short8*)&p[c0] = o;
    }
  }
}

// ==== 128x128 GEMM, BK=32, depth-3 LDS ring (48KB -> 3 blk/CU), 4 waves ===
// ONE barrier per K-tile; stage distance 1; counted vmcnt(4) (no mid-loop
// drain). Race-free: stage(tt+1) overwrites buf[(tt-2)%3], whose readers all
// finished before bar(tt-1). Chunk swizzle phys = g ^ ((row>>1)&3): exactly
// 2 lanes/16B-slot (2-way = free, m136); source-side XOR involution.
// causal: 0 none; 1 mask; 2 K-trunc; 3 triangular grid (S);
//         4 K-trunc + balanced remap (PV).
template <int OUTBF>
__global__ __launch_bounds__(256, 3) void gemm128_kernel(
    const unsigned short* __restrict__ A, int lda, long long saz,
    const unsigned short* __restrict__ Bt, int ldb, long long sbz,
    void* __restrict__ Cv, int ldc, long long scz,
    const float* __restrict__ bias, int K, float scale, int causal) {
  // 3 bufs x 8192 shorts; per buf: A [0,4096) = 128r x 32c, B [4096,8192)
  __shared__ __align__(16) unsigned short lds[3][8192];

  int bx, by, z;
  if (causal == 3) {
    int i = blockIdx.x;
    by = (int)((sqrtf(8.f * i + 1.f) - 1.f) * 0.5f);
    while ((by + 1) * (by + 2) / 2 <= i) by++;
    while (by * (by + 1) / 2 > i) by--;
    bx = i - by * (by + 1) / 2;
    z = blockIdx.y;
  } else if (causal == 4) {
    int gx = gridDim.x, gy = gridDim.y, gz = gridDim.z;
    int total = gx * gy * gz;
    int id = blockIdx.x + blockIdx.y * gx + blockIdx.z * gx * gy;
    int halfn = total >> 1;
    int half = id >= halfn;
    int r = id - half * halfn;
    bx = r % gx;
    int rest = r / gx;
    int by0 = rest % gy;
    z = rest / gy + half * (gz >> 1);
    by = half ? (gy - 1 - by0) : by0;
  } else {
    bx = blockIdx.x; by = blockIdx.y; z = blockIdx.z;
  }
  const int m0 = by * 128, n0 = bx * 128;
  A += (size_t)z * saz;
  Bt += (size_t)z * sbz;

  const int t = threadIdx.x;
  const int lane = t & 63, wid = t >> 6;
  const int g = lane >> 4, q = lane & 15;
  const int wm = wid >> 1, wn = wid & 1;  // wave tile 64x64

  int NT = K >> 5;
  if (causal == 1) { if (n0 >= m0 + 128) NT = 0; }
  else if (causal == 2 || causal == 4) { NT = min(K, m0 + 128) >> 5; }

  f32x4 acc[4][4] = {};

  if (NT > 0) {
    // staging: thread t writes 16B linearly at row=(t>>2), phys chunk=(t&3);
    // source chunk pre-swizzled (involution): (t&3) ^ ((t>>3)&3)
    const int scol = ((t & 3) ^ ((t >> 3) & 3)) * 8;
    const unsigned short* aS = A + (size_t)(m0 + (t >> 2)) * lda + scol;
    const unsigned short* bS = Bt + (size_t)(n0 + (t >> 2)) * ldb + scol;

    auto stage = [&](int tt, int buf) {
      unsigned short* d = &lds[buf][wid * 512];
      const unsigned short* sa = aS + (size_t)tt * 32;
      const unsigned short* sb = bS + (size_t)tt * 32;
      gload16(sa, d);                            // A rows 0-63
      gload16(sa + (size_t)64 * lda, d + 2048);  // A rows 64-127
      gload16(sb, d + 4096);                     // B rows 0-63
      gload16(sb + (size_t)64 * ldb, d + 6144);  // B rows 64-127
    };

    // read addresses (bytes); phys chunk = g ^ ((q>>1)&3)
    const unsigned base =
        (unsigned)(unsigned long long)(__attribute__((address_space(3))) unsigned short*)&lds[0][0];
    const int cb = ((g ^ ((q >> 1) & 3)) << 4);  // chunk byte offset
    const unsigned aaB = base + (unsigned)((wm * 64 + q) * 64 + cb);
    const unsigned bbB = base + 8192u + (unsigned)((wn * 64 + q) * 64 + cb);

    stage(0, 0);

    auto body = [&](auto dbc, int tt) {
      constexpr int DB = decltype(dbc)::value;
      if (tt + 1 < NT) {
        stage(tt + 1, (DB + 1) % 3);
        asm volatile("s_waitcnt vmcnt(4)" ::: "memory");  // own tile-tt loads done
      } else {
        asm volatile("s_waitcnt vmcnt(0)" ::: "memory");
      }
      bar();  // whole tile tt in LDS
      const unsigned aa = aaB + DB * 16384u;
      const unsigned bb = bbB + DB * 16384u;
      short8 aq[4], bq[4];
      aq[0] = dsr<0>(aa);
      aq[1] = dsr<1024>(aa);
      aq[2] = dsr<2048>(aa);
      aq[3] = dsr<3072>(aa);
      bq[0] = dsr<0>(bb);
      bq[1] = dsr<1024>(bb);
      bq[2] = dsr<2048>(bb);
      bq[3] = dsr<3072>(bb);
      asm volatile("s_waitcnt lgkmcnt(0)" ::: "memory");
      __builtin_amdgcn_sched_barrier(0);
      __builtin_amdgcn_s_setprio(1);
#pragma unroll
      for (int m = 0; m < 4; m++)
#pragma unroll
        for (int n = 0; n < 4; n++)
          acc[m][n] = __builtin_amdgcn_mfma_f32_16x16x32_bf16(aq[m], bq[n], acc[m][n], 0, 0, 0);
      __builtin_amdgcn_s_setprio(0);
      __builtin_amdgcn_sched_barrier(0);
    };

    int tt = 0;
    for (; tt + 3 <= NT; tt += 3) {
      body(DB0{}, tt);
      body(DB1{}, tt + 1);
      body(DB2{}, tt + 2);
    }
    if (tt < NT) body(DB0{}, tt);
    if (tt + 1 < NT) body(DB1{}, tt + 1);
  }

  // ---- epilogue ----
  const bool maskC = (causal == 1) || (causal == 3);
#pragma unroll
  for (int n = 0; n < 4; n++) {
    int colg = n0 + wn * 64 + n * 16 + q;
    float bv = bias ? bias[colg] : 0.f;
#pragma unroll
    for (int m = 0; m < 4; m++) {
      int rowb = m0 + wm * 64 + m * 16 + g * 4;
#pragma unroll
      for (int r = 0; r < 4; r++) {
        float val = acc[m][n][r] * scale + bv;
        if (maskC && colg > rowb + r) val = -1e30f;
        if (OUTBF) {
          ((unsigned short*)Cv)[(size_t)z * scz + (size_t)(rowb + r) * ldc + colg] = f2bf(val);
        } else {
          ((float*)Cv)[(size_t)z * scz + (size_t)(rowb + r) * ldc + colg] = val;
        }
      }
    }
  }
}

extern "C" void kernel_launch(void* const* d_in, const int* in_sizes, int n_in,
                              void* d_out, int out_size, void* d_ws, size_t ws_size,
                              hipStream_t stream) {
  const float* x  = (const float*)d_in[0];
  const float* Wa = (const float*)d_in[1];
  const float* ba = (const float*)d_in[2];
  const float* Wp = (const float*)d_in[3];
  const float* bp = (const float*)d_in[4];
  float* out = (float*)d_out;

  char* ws = (char*)d_ws;
  unsigned short* qkv = (unsigned short*)(ws);                 // 50331648
  unsigned short* xb  = (unsigned short*)(ws + 50331648);      // 16777216
  unsigned short* vt  = (unsigned short*)(ws + 50331648);      // V'^T, overlays xb
  unsigned short* wta = (unsigned short*)(ws + 67108864);      // 6291456
  unsigned short* S   = (unsigned short*)(ws + 73400320);      // 33554432
  unsigned short* wtp = (unsigned short*)(ws + 123731968);     // 2097152

  prep_kernel<<<12288, 256, 0, stream>>>(x, xb, Wa, wta, Wp, wtp);

  // qkv = x @ W_attn + b_attn   [8192 x 3072]
  gemm128_kernel<1><<<dim3(24, 64, 1), 256, 0, stream>>>(
      xb, 1024, 0, wta, 1024, 0, qkv, 3072, 0, ba, 1024, 1.0f, 0);

  // S = Q @ K^T * 0.125, lower-triangle blocks only (136 per batch)
  gemm128_kernel<1><<<dim3(136, 4), 256, 0, stream>>>(
      qkv, 3072, 2048LL * 3072, qkv + 1024, 3072, 2048LL * 3072,
      S, 2048, 2048LL * 2048, nullptr, 1024, 0.125f, 3);

  softmax_kernel<<<2048, 256, 0, stream>>>(S);

  // V'^T = Wp^T @ V^T : [1024 x 2048] per batch; A=wtp, Bt=V-part of qkv
  gemm128_kernel<1><<<dim3(16, 8, 4), 256, 0, stream>>>(
      wtp, 1024, 0, qkv + 2048, 3072, 2048LL * 3072,
      vt, 2048, 2048LL * 1024, nullptr, 1024, 1.0f, 0);

  // out = P @ V' + b_proj : [2048 x 1024] per batch, fp32, K-trunc balanced
  gemm128_kernel<0><<<dim3(8, 16, 4), 256, 0, stream>>>(
      S, 2048, 2048LL * 2048, vt, 2048, 2048LL * 1024,
      out, 1024, 2048LL * 1024, bp, 2048, 1.0f, 4);
}